// Round 2
// baseline (237.363 us; speedup 1.0000x reference)
//
#include <hip/hip_runtime.h>
#include <hip/hip_bf16.h>

typedef unsigned short u16;
typedef __attribute__((ext_vector_type(4))) float f32x4;
typedef __attribute__((ext_vector_type(8))) short short8;     // 8 bf16 (4 VGPRs) MFMA frag
typedef __attribute__((ext_vector_type(8))) unsigned short u16x8;
typedef __attribute__((ext_vector_type(4))) unsigned short u16x4;

// B=2, S=2048, E=1024, H=16, HD=64
#define BATCH 2
#define SEQ   2048
#define EMB   1024
#define NH    16
#define HD    64

__device__ inline u16 f2bf(float f) {
    unsigned u = __builtin_bit_cast(unsigned, f);
    unsigned r = u + 0x7FFFu + ((u >> 16) & 1u);   // RNE
    return (u16)(r >> 16);
}

// ---------------------------------------------------------------------------
// GEMM C[m][n] = sum_k A[m][k] * W[n][k]   (B^T layout, K=1024, BK=32)
// BM=BN=128, 256 threads = 4 waves (2x2), each wave 64x64 = 4x4 frags 16x16.
// MODE 0: A = x (f32), W in {Wq,Wk,Wv} by n-tile; epilogue -> Q,K [B,H,S,64] bf16,
//         V transposed -> VT [B,H,64,S] bf16.
// MODE 1: A = cat (bf16), W = Wo (f32); epilogue -> f32 out [B,S,E].
// ---------------------------------------------------------------------------
#define LDT 40   // LDS row stride (elems): 32 + 8 pad -> 80B rows, conflict-light

template<int MODE>
__global__ __launch_bounds__(256) void gemm_bt(
    const float* __restrict__ Af, const u16* __restrict__ Ab,
    const float* __restrict__ W0, const float* __restrict__ W1, const float* __restrict__ W2,
    u16* __restrict__ Qo, u16* __restrict__ Ko, u16* __restrict__ VTo,
    float* __restrict__ Fo)
{
    __shared__ u16 As[128 * LDT];
    __shared__ u16 Bs[128 * LDT];

    const int tid = threadIdx.x;
    const int m0 = blockIdx.x * 128;
    const int n0 = blockIdx.y * 128;

    const float* Wf;
    int nr0;
    if (MODE == 0) {
        const int w = n0 >> 10;                 // which weight (block-uniform)
        Wf = (w == 0) ? W0 : (w == 1) ? W1 : W2;
        nr0 = n0 & 1023;                        // row offset inside that weight
    } else {
        Wf = W0;
        nr0 = n0;
    }

    const int lane = tid & 63;
    const int lr = lane & 15;      // frag row/col index
    const int lg = lane >> 4;      // k-group
    const int wid = tid >> 6;
    const int wm = wid >> 1, wn = wid & 1;

    f32x4 acc[4][4] = {};

    for (int kt = 0; kt < 32; ++kt) {
        const int k0 = kt * 32;
        __syncthreads();
        // ---- stage A tile [128][32] ----
        #pragma unroll
        for (int c = tid; c < 512; c += 256) {
            const int row = c >> 2, kc = c & 3;
            u16x8 wv;
            if (MODE == 0) {
                const float* g = Af + (size_t)(m0 + row) * EMB + k0 + kc * 8;
                f32x4 v0 = *(const f32x4*)g;
                f32x4 v1 = *(const f32x4*)(g + 4);
                #pragma unroll
                for (int j = 0; j < 4; ++j) { wv[j] = f2bf(v0[j]); wv[4 + j] = f2bf(v1[j]); }
            } else {
                wv = *(const u16x8*)(Ab + (size_t)(m0 + row) * EMB + k0 + kc * 8);
            }
            *(u16x8*)&As[row * LDT + kc * 8] = wv;
        }
        // ---- stage B tile [128][32] (always f32 source) ----
        #pragma unroll
        for (int c = tid; c < 512; c += 256) {
            const int row = c >> 2, kc = c & 3;
            const float* g = Wf + (size_t)(nr0 + row) * EMB + k0 + kc * 8;
            f32x4 v0 = *(const f32x4*)g;
            f32x4 v1 = *(const f32x4*)(g + 4);
            u16x8 wv;
            #pragma unroll
            for (int j = 0; j < 4; ++j) { wv[j] = f2bf(v0[j]); wv[4 + j] = f2bf(v1[j]); }
            *(u16x8*)&Bs[row * LDT + kc * 8] = wv;
        }
        __syncthreads();

        short8 a[4], b[4];
        #pragma unroll
        for (int i = 0; i < 4; ++i)
            a[i] = *(const short8*)&As[(wm * 64 + i * 16 + lr) * LDT + lg * 8];
        #pragma unroll
        for (int i = 0; i < 4; ++i)
            b[i] = *(const short8*)&Bs[(wn * 64 + i * 16 + lr) * LDT + lg * 8];
        #pragma unroll
        for (int mi = 0; mi < 4; ++mi)
            #pragma unroll
            for (int ni = 0; ni < 4; ++ni)
                acc[mi][ni] = __builtin_amdgcn_mfma_f32_16x16x32_bf16(a[mi], b[ni], acc[mi][ni], 0, 0, 0);
    }

    // ---- epilogue: C layout col = lane&15, row = (lane>>4)*4 + i ----
    const int mb = m0 + wm * 64;
    const int nb = n0 + wn * 64;
    if (MODE == 0) {
        const int w = n0 >> 10;
        #pragma unroll
        for (int mi = 0; mi < 4; ++mi) {
            #pragma unroll
            for (int ni = 0; ni < 4; ++ni) {
                const int m = mb + mi * 16 + lg * 4;       // +i for i=0..3
                const int nn = (nb + ni * 16 + lr) & 1023;
                const int h = nn >> 6, d = nn & 63;
                const int bb = m >> 11, s = m & 2047;
                const size_t bh = (size_t)(bb * NH + h);
                if (w == 2) {
                    u16x4 v;
                    #pragma unroll
                    for (int i = 0; i < 4; ++i) v[i] = f2bf(acc[mi][ni][i]);
                    *(u16x4*)&VTo[(bh * HD + d) * SEQ + s] = v;   // s%4==0 -> 8B aligned
                } else {
                    u16* P = (w == 0) ? Qo : Ko;
                    #pragma unroll
                    for (int i = 0; i < 4; ++i)
                        P[(bh * SEQ + s + i) * HD + d] = f2bf(acc[mi][ni][i]);
                }
            }
        }
    } else {
        #pragma unroll
        for (int mi = 0; mi < 4; ++mi)
            #pragma unroll
            for (int ni = 0; ni < 4; ++ni) {
                const int m = mb + mi * 16 + lg * 4;
                const int n = nb + ni * 16 + lr;
                #pragma unroll
                for (int i = 0; i < 4; ++i)
                    Fo[(size_t)(m + i) * EMB + n] = acc[mi][ni][i];
            }
    }
}

// ---------------------------------------------------------------------------
// Flash attention: grid (S/64, B*H), 256 threads = 4 waves, 16 q-rows/wave.
// Q,K: [B,H,S,64] bf16; VT: [B,H,64,S] bf16. Online softmax in f32.
// Writes cat [B,S,E] bf16.
// ---------------------------------------------------------------------------
__global__ __launch_bounds__(256) void attn_fwd(
    const u16* __restrict__ Q, const u16* __restrict__ K,
    const u16* __restrict__ VT, u16* __restrict__ Cat)
{
    __shared__ u16 Ks[64 * 72];       // [kv][e]  (72-elem stride: pad)
    __shared__ u16 Vs[64 * 72];       // [d][kv]
    __shared__ u16 Ps[4][16 * 72];    // per-wave P [qrow][kv]

    const int tid = threadIdx.x;
    const int lane = tid & 63;
    const int lr = lane & 15;
    const int lg = lane >> 4;
    const int wid = tid >> 6;
    const int qt = blockIdx.x;
    const int bh = blockIdx.y;
    const int b = bh >> 4, h = bh & 15;

    // Q fragments (A operand): row = lane%16, k = 32*kk + 8*lg + j
    const u16* Qg = Q + ((size_t)bh * SEQ + qt * 64 + wid * 16 + lr) * HD;
    short8 qf[2];
    qf[0] = *(const short8*)(Qg + 0 * 32 + lg * 8);
    qf[1] = *(const short8*)(Qg + 1 * 32 + lg * 8);

    float mrow[4], lrow[4];
    f32x4 accO[4] = {};
    #pragma unroll
    for (int i = 0; i < 4; ++i) { mrow[i] = -1e30f; lrow[i] = 0.f; }

    const u16* Kg = K + (size_t)bh * SEQ * HD;
    const u16* Vg = VT + (size_t)bh * HD * SEQ;

    for (int nt = 0; nt < SEQ / 64; ++nt) {
        const int kv0 = nt * 64;
        __syncthreads();   // previous iteration's LDS reads done
        // ---- stage K [64 kv][64 e] and VT [64 d][64 kv] ----
        #pragma unroll
        for (int c = tid; c < 512; c += 256) {
            const int row = c >> 3, kc = c & 7;
            *(u16x8*)&Ks[row * 72 + kc * 8] =
                *(const u16x8*)(Kg + (size_t)(kv0 + row) * HD + kc * 8);
            *(u16x8*)&Vs[row * 72 + kc * 8] =
                *(const u16x8*)(Vg + (size_t)row * SEQ + kv0 + kc * 8);
        }
        __syncthreads();

        // ---- S = Q K^T / 8 : 16x64 per wave in 4 frags ----
        f32x4 sc[4] = {};
        #pragma unroll
        for (int kk = 0; kk < 2; ++kk) {
            const short8 qv = qf[kk];
            #pragma unroll
            for (int c = 0; c < 4; ++c) {
                const short8 kf = *(const short8*)&Ks[(c * 16 + lr) * 72 + kk * 32 + lg * 8];
                sc[c] = __builtin_amdgcn_mfma_f32_16x16x32_bf16(qv, kf, sc[c], 0, 0, 0);
            }
        }

        // ---- online softmax (rows r = lg*4+i live in the 16 lanes of group lg) ----
        float rmax[4] = {-1e30f, -1e30f, -1e30f, -1e30f};
        #pragma unroll
        for (int c = 0; c < 4; ++c)
            #pragma unroll
            for (int i = 0; i < 4; ++i) {
                sc[c][i] *= 0.125f;
                rmax[i] = fmaxf(rmax[i], sc[c][i]);
            }
        #pragma unroll
        for (int i = 0; i < 4; ++i) {
            #pragma unroll
            for (int off = 1; off < 16; off <<= 1)
                rmax[i] = fmaxf(rmax[i], __shfl_xor(rmax[i], off));
        }
        float al[4], rs[4] = {0.f, 0.f, 0.f, 0.f};
        #pragma unroll
        for (int i = 0; i < 4; ++i) {
            const float mn = fmaxf(mrow[i], rmax[i]);
            al[i] = __expf(mrow[i] - mn);
            mrow[i] = mn;
        }
        #pragma unroll
        for (int c = 0; c < 4; ++c)
            #pragma unroll
            for (int i = 0; i < 4; ++i) {
                const float p = __expf(sc[c][i] - mrow[i]);
                sc[c][i] = p;
                rs[i] += p;
            }
        #pragma unroll
        for (int i = 0; i < 4; ++i) {
            #pragma unroll
            for (int off = 1; off < 16; off <<= 1)
                rs[i] += __shfl_xor(rs[i], off);
            lrow[i] = lrow[i] * al[i] + rs[i];
        }
        #pragma unroll
        for (int dc = 0; dc < 4; ++dc)
            #pragma unroll
            for (int i = 0; i < 4; ++i)
                accO[dc][i] *= al[i];

        // ---- P -> LDS bf16 [qrow][kv] (scalar writes; vector reads) ----
        u16* pw = &Ps[wid][0];
        #pragma unroll
        for (int c = 0; c < 4; ++c)
            #pragma unroll
            for (int i = 0; i < 4; ++i)
                pw[(lg * 4 + i) * 72 + c * 16 + lr] = f2bf(sc[c][i]);
        __syncthreads();   // make P visible across lanes (wave-private but cross-lane)

        // ---- O += P V : A=P[16x64], B=VT frags ----
        #pragma unroll
        for (int kk = 0; kk < 2; ++kk) {
            const short8 pf = *(const short8*)&Ps[wid][lr * 72 + kk * 32 + lg * 8];
            #pragma unroll
            for (int dc = 0; dc < 4; ++dc) {
                const short8 vf = *(const short8*)&Vs[(dc * 16 + lr) * 72 + kk * 32 + lg * 8];
                accO[dc] = __builtin_amdgcn_mfma_f32_16x16x32_bf16(pf, vf, accO[dc], 0, 0, 0);
            }
        }
    }

    // ---- epilogue: cat[b, s, h*64+d] = O / l ----
    const int s0 = qt * 64 + wid * 16 + lg * 4;
    const size_t obase = (size_t)b * SEQ * EMB;
    #pragma unroll
    for (int dc = 0; dc < 4; ++dc)
        #pragma unroll
        for (int i = 0; i < 4; ++i) {
            const float o = accO[dc][i] / lrow[i];
            Cat[obase + (size_t)(s0 + i) * EMB + h * HD + dc * 16 + lr] = f2bf(o);
        }
}

// ---------------------------------------------------------------------------
extern "C" void kernel_launch(void* const* d_in, const int* in_sizes, int n_in,
                              void* d_out, int out_size, void* d_ws, size_t ws_size,
                              hipStream_t stream) {
    const float* x  = (const float*)d_in[0];
    const float* Wq = (const float*)d_in[1];
    const float* Wk = (const float*)d_in[2];
    const float* Wv = (const float*)d_in[3];
    const float* Wo = (const float*)d_in[4];
    float* out = (float*)d_out;

    char* ws = (char*)d_ws;
    u16* Qb  = (u16*)(ws);                        // [B,H,S,64]  8MB
    u16* Kb  = (u16*)(ws + (size_t)8  * 1048576); // [B,H,S,64]  8MB
    u16* VTb = (u16*)(ws + (size_t)16 * 1048576); // [B,H,64,S]  8MB
    u16* Cat = (u16*)(ws + (size_t)24 * 1048576); // [B,S,E]     8MB

    // QKV projection: M=4096, N=3072, K=1024
    dim3 g1(4096 / 128, 3072 / 128);
    gemm_bt<0><<<g1, 256, 0, stream>>>(x, nullptr, Wq, Wk, Wv, Qb, Kb, VTb, nullptr);

    // Attention
    dim3 g2(SEQ / 64, BATCH * NH);
    attn_fwd<<<g2, 256, 0, stream>>>(Qb, Kb, VTb, Cat);

    // Output projection: M=4096, N=1024, K=1024
    dim3 g3(4096 / 128, 1024 / 128);
    gemm_bt<1><<<g3, 256, 0, stream>>>(nullptr, Cat, Wo, nullptr, nullptr,
                                       nullptr, nullptr, nullptr, out);
}

// Round 3
// 168.403 us; speedup vs baseline: 1.4095x; 1.4095x over previous
//
#include <hip/hip_runtime.h>
#include <hip/hip_bf16.h>

typedef unsigned short u16;
typedef unsigned int u32;
typedef __attribute__((ext_vector_type(4))) float f32x4;
typedef __attribute__((ext_vector_type(8))) short short8;     // 8 bf16 MFMA frag
typedef __attribute__((ext_vector_type(8))) unsigned short u16x8;
typedef __attribute__((ext_vector_type(4))) unsigned short u16x4;
typedef __attribute__((ext_vector_type(2))) unsigned int u32x2;

// B=2, S=2048, E=1024, H=16, HD=64
#define BATCH 2
#define SEQ   2048
#define EMB   1024
#define NH    16
#define HD    64

__device__ inline u16 f2bf(float f) {
    unsigned u = __builtin_bit_cast(unsigned, f);
    unsigned r = u + 0x7FFFu + ((u >> 16) & 1u);   // RNE
    return (u16)(r >> 16);
}

__device__ inline void gload16(const void* g, void* l) {
    __builtin_amdgcn_global_load_lds(
        (const __attribute__((address_space(1))) unsigned int*)g,
        (__attribute__((address_space(3))) unsigned int*)l, 16, 0, 0);
}

// ---------------------------------------------------------------------------
// convert: x (4M f32) -> Xb bf16 ; Wq|Wk|Wv (3M f32) -> Wqkv bf16
// grid 3584 x 256, 8 elems/thread
// ---------------------------------------------------------------------------
__global__ __launch_bounds__(256) void convert_all(
    const float* __restrict__ x,
    const float* __restrict__ Wq, const float* __restrict__ Wk, const float* __restrict__ Wv,
    u16* __restrict__ Xb, u16* __restrict__ Wqkv)
{
    const long gidx = (long)blockIdx.x * 2048 + (long)threadIdx.x * 8;
    const float* src;
    u16* dst;
    if (gidx < 4194304L) {
        src = x + gidx; dst = Xb + gidx;
    } else {
        const long r = gidx - 4194304L;
        const int w = (int)(r >> 20);
        const long off = r & 1048575L;
        src = (w == 0 ? Wq : w == 1 ? Wk : Wv) + off;
        dst = Wqkv + r;
    }
    f32x4 a = *(const f32x4*)src;
    f32x4 b = *(const f32x4*)(src + 4);
    u16x8 o;
    #pragma unroll
    for (int j = 0; j < 4; ++j) { o[j] = f2bf(a[j]); o[4 + j] = f2bf(b[j]); }
    *(u16x8*)dst = o;
}

// ---------------------------------------------------------------------------
// GEMM C[m][n] = sum_k A[m][k] * B[n][k]   (K=1024, BK=32, 128x128 tile)
// A always bf16 via global_load_lds. MODE 0: B bf16 (Wqkv) via global_load_lds,
// epilogue scatters Q(x0.125),K -> [B,H,S,64], V -> VT [B,H,64,S].
// MODE 1: B f32 (Wo) reg-staged; epilogue f32 out.
// LDS: linear [128][32] bf16 (64B rows) — m97 geometry.
// ---------------------------------------------------------------------------
template<int MODE>
__global__ __launch_bounds__(256) void gemm_bt(
    const u16* __restrict__ A, const u16* __restrict__ Bb, const float* __restrict__ Bf,
    u16* __restrict__ Qo, u16* __restrict__ Ko, u16* __restrict__ VTo,
    float* __restrict__ Fo)
{
    __shared__ u16 As[128 * 32];
    __shared__ u16 Bs[128 * 32];

    const int tid = threadIdx.x;
    const int m0 = blockIdx.x * 128;
    const int n0 = blockIdx.y * 128;

    const int lane = tid & 63;
    const int lr = lane & 15;
    const int lg = lane >> 4;
    const int wid = tid >> 6;
    const int wm = wid >> 1, wn = wid & 1;

    // global_load_lds per-issue geometry: wave issue t covers LDS bytes
    // (wid*2+t)*1024 .. +1023 = rows (wid*2+t)*16+(lane>>2), col (lane&3)*8 elems
    const int grow0 = (lane >> 2);
    const int gcolb = (lane & 3) * 16;     // byte offset in 64B row

    f32x4 acc[4][4] = {};

    for (int kt = 0; kt < 32; ++kt) {
        const int k0b = kt * 64;           // byte offset of k0 in 2048B row
        __syncthreads();
        // ---- A stage: 2 issues per wave ----
        #pragma unroll
        for (int t = 0; t < 2; ++t) {
            const int row = (wid * 2 + t) * 16 + grow0;
            gload16((const char*)A + (size_t)(m0 + row) * 2048 + k0b + gcolb,
                    (char*)As + (wid * 2 + t) * 1024);
        }
        // ---- B stage ----
        if (MODE == 0) {
            #pragma unroll
            for (int t = 0; t < 2; ++t) {
                const int row = (wid * 2 + t) * 16 + grow0;
                gload16((const char*)Bb + (size_t)(n0 + row) * 2048 + k0b + gcolb,
                        (char*)Bs + (wid * 2 + t) * 1024);
            }
        } else {
            #pragma unroll
            for (int c = tid; c < 512; c += 256) {
                const int row = c >> 2, kc = c & 3;
                const float* g = Bf + (size_t)(n0 + row) * EMB + kt * 32 + kc * 8;
                f32x4 v0 = *(const f32x4*)g;
                f32x4 v1 = *(const f32x4*)(g + 4);
                u16x8 wv;
                #pragma unroll
                for (int j = 0; j < 4; ++j) { wv[j] = f2bf(v0[j]); wv[4 + j] = f2bf(v1[j]); }
                *(u16x8*)((char*)Bs + row * 64 + kc * 16) = wv;
            }
        }
        __syncthreads();

        short8 a[4], b[4];
        #pragma unroll
        for (int i = 0; i < 4; ++i)
            a[i] = *(const short8*)((const char*)As + (wm * 64 + i * 16 + lr) * 64 + lg * 16);
        #pragma unroll
        for (int i = 0; i < 4; ++i)
            b[i] = *(const short8*)((const char*)Bs + (wn * 64 + i * 16 + lr) * 64 + lg * 16);
        #pragma unroll
        for (int mi = 0; mi < 4; ++mi)
            #pragma unroll
            for (int ni = 0; ni < 4; ++ni)
                acc[mi][ni] = __builtin_amdgcn_mfma_f32_16x16x32_bf16(a[mi], b[ni], acc[mi][ni], 0, 0, 0);
    }

    // ---- epilogue: C col = lane&15, row = (lane>>4)*4 + i ----
    const int mb = m0 + wm * 64;
    const int nb = n0 + wn * 64;
    if (MODE == 0) {
        const int w = n0 >> 10;
        const float qs = (w == 0) ? 0.125f : 1.0f;
        #pragma unroll
        for (int mi = 0; mi < 4; ++mi) {
            #pragma unroll
            for (int ni = 0; ni < 4; ++ni) {
                const int m = mb + mi * 16 + lg * 4;
                const int nn = (nb + ni * 16 + lr) & 1023;
                const int h = nn >> 6, d = nn & 63;
                const int bb = m >> 11, s = m & 2047;
                const size_t bh = (size_t)(bb * NH + h);
                if (w == 2) {
                    u16x4 v;
                    #pragma unroll
                    for (int i = 0; i < 4; ++i) v[i] = f2bf(acc[mi][ni][i]);
                    *(u16x4*)&VTo[(bh * HD + d) * SEQ + s] = v;
                } else {
                    u16* P = (w == 0) ? Qo : Ko;
                    #pragma unroll
                    for (int i = 0; i < 4; ++i)
                        P[(bh * SEQ + s + i) * HD + d] = f2bf(acc[mi][ni][i] * qs);
                }
            }
        }
    } else {
        #pragma unroll
        for (int mi = 0; mi < 4; ++mi)
            #pragma unroll
            for (int ni = 0; ni < 4; ++ni) {
                const int m = mb + mi * 16 + lg * 4;
                const int n = nb + ni * 16 + lr;
                #pragma unroll
                for (int i = 0; i < 4; ++i)
                    Fo[(size_t)(m + i) * EMB + n] = acc[mi][ni][i];
            }
    }
}

// ---------------------------------------------------------------------------
// Flash attention, swapped-operand form. grid (S/64, B*H), 4 waves, 16 q/wave.
// ST[kv][q] = mfma(Kfrag, Qfrag): lane owns q=lr, kv = c*16+lg*4+i.
// Softmax per-lane scalar m,l; P packed via v_cvt_pk_bf16_f32 -> per-wave
// LDS tile PT[q=16][kv=64] -> B-operand of OT[d][q] = mfma(VTfrag, Pfrag).
// K/V LDS: linear [64][64] bf16 (128B rows) + XOR swizzle byte^=((row&7)<<4).
// ---------------------------------------------------------------------------
__global__ __launch_bounds__(256) void attn_fwd(
    const u16* __restrict__ Q, const u16* __restrict__ K,
    const u16* __restrict__ VT, u16* __restrict__ Cat)
{
    __shared__ u16 Ks[64 * 64];
    __shared__ u16 Vs[64 * 64];
    __shared__ u16 PT[4][16 * 72];     // per-wave, pad-72

    const int tid = threadIdx.x;
    const int lane = tid & 63;
    const int lr = lane & 15;
    const int lg = lane >> 4;
    const int wid = tid >> 6;
    const int qt = blockIdx.x;
    const int bh = blockIdx.y;
    const int b = bh >> 4, h = bh & 15;

    // Q fragments (B operand): col = lr <-> q, k = kk*32 + lg*8 + j
    const u16* Qg = Q + ((size_t)bh * SEQ + qt * 64 + wid * 16 + lr) * HD;
    short8 qf[2];
    qf[0] = *(const short8*)(Qg + lg * 8);
    qf[1] = *(const short8*)(Qg + 32 + lg * 8);

    float m = -1e30f, l = 0.f;
    f32x4 accO[4] = {};

    const u16* Kg = K + (size_t)bh * SEQ * HD;
    const u16* Vg = VT + (size_t)bh * HD * SEQ;
    const int kxor = (lr & 7) << 4;

    for (int nt = 0; nt < SEQ / 64; ++nt) {
        const int kv0 = nt * 64;
        __syncthreads();
        // ---- stage K [64 kv][64 e], VT [64 d][64 kv], XOR-swizzled ----
        #pragma unroll
        for (int c = tid; c < 512; c += 256) {
            const int row = c >> 3, sl = c & 7;
            const u16x8 kv8 = *(const u16x8*)(Kg + (size_t)(kv0 + row) * HD + sl * 8);
            const u16x8 vv8 = *(const u16x8*)(Vg + (size_t)row * SEQ + kv0 + sl * 8);
            const int so = ((sl ^ (row & 7)) << 4);
            *(u16x8*)((char*)Ks + row * 128 + so) = kv8;
            *(u16x8*)((char*)Vs + row * 128 + so) = vv8;
        }
        __syncthreads();

        // ---- ST = K Q^T (swapped): st[c] covers kv rows c*16..+15 ----
        f32x4 st[4] = {};
        #pragma unroll
        for (int kk = 0; kk < 2; ++kk) {
            const short8 qv = qf[kk];
            #pragma unroll
            for (int c = 0; c < 4; ++c) {
                const short8 kf = *(const short8*)((const char*)Ks + (c * 16 + lr) * 128
                                                   + (((kk * 4 + lg) ^ (lr & 7)) << 4));
                st[c] = __builtin_amdgcn_mfma_f32_16x16x32_bf16(kf, qv, st[c], 0, 0, 0);
            }
        }

        // ---- online softmax: lane owns q = lr (16 kv values local) ----
        float mx = st[0][0];
        #pragma unroll
        for (int c = 0; c < 4; ++c)
            #pragma unroll
            for (int i = 0; i < 4; ++i)
                mx = fmaxf(mx, st[c][i]);
        mx = fmaxf(mx, __shfl_xor(mx, 16));
        mx = fmaxf(mx, __shfl_xor(mx, 32));
        const float mnew = fmaxf(m, mx);
        const float corr = __expf(m - mnew);
        m = mnew;
        float sum = 0.f;
        #pragma unroll
        for (int c = 0; c < 4; ++c)
            #pragma unroll
            for (int i = 0; i < 4; ++i) {
                const float p = __expf(st[c][i] - m);
                st[c][i] = p;
                sum += p;
            }
        sum += __shfl_xor(sum, 16);
        sum += __shfl_xor(sum, 32);
        l = l * corr + sum;
        #pragma unroll
        for (int dc = 0; dc < 4; ++dc)
            accO[dc] *= corr;

        // ---- P pack (bf16 pairs, kv-contiguous) -> PT[q=lr][kv] ----
        #pragma unroll
        for (int c = 0; c < 4; ++c) {
            u32 w0, w1;
            asm("v_cvt_pk_bf16_f32 %0, %1, %2" : "=v"(w0) : "v"(st[c][0]), "v"(st[c][1]));
            asm("v_cvt_pk_bf16_f32 %0, %1, %2" : "=v"(w1) : "v"(st[c][2]), "v"(st[c][3]));
            u32x2 pk; pk[0] = w0; pk[1] = w1;
            *(u32x2*)&PT[wid][lr * 72 + c * 16 + lg * 4] = pk;
        }
        asm volatile("s_waitcnt lgkmcnt(0)" ::: "memory");
        __builtin_amdgcn_sched_barrier(0);

        // ---- O^T += V^T P : A = VT frag (row=d), B = P (col=q, k=kv) ----
        #pragma unroll
        for (int kk = 0; kk < 2; ++kk) {
            const short8 pf = *(const short8*)&PT[wid][lr * 72 + kk * 32 + lg * 8];
            #pragma unroll
            for (int dc = 0; dc < 4; ++dc) {
                const short8 vf = *(const short8*)((const char*)Vs + (dc * 16 + lr) * 128
                                                   + (((kk * 4 + lg) ^ (lr & 7)) << 4));
                accO[dc] = __builtin_amdgcn_mfma_f32_16x16x32_bf16(vf, pf, accO[dc], 0, 0, 0);
            }
        }
    }

    // ---- epilogue: lane q = lr; d = dc*16 + lg*4 + i (contiguous i) ----
    const float invl = 1.f / l;
    const int qs = qt * 64 + wid * 16 + lr;
    u16* ob = Cat + (size_t)b * SEQ * EMB + (size_t)qs * EMB + h * HD;
    #pragma unroll
    for (int dc = 0; dc < 4; ++dc) {
        u16x4 o;
        #pragma unroll
        for (int i = 0; i < 4; ++i) o[i] = f2bf(accO[dc][i] * invl);
        *(u16x4*)&ob[dc * 16 + lg * 4] = o;
    }
}

// ---------------------------------------------------------------------------
extern "C" void kernel_launch(void* const* d_in, const int* in_sizes, int n_in,
                              void* d_out, int out_size, void* d_ws, size_t ws_size,
                              hipStream_t stream) {
    const float* x  = (const float*)d_in[0];
    const float* Wq = (const float*)d_in[1];
    const float* Wk = (const float*)d_in[2];
    const float* Wv = (const float*)d_in[3];
    const float* Wo = (const float*)d_in[4];
    float* out = (float*)d_out;

    // d_out (16MB f32) doubles as bf16 staging: Xb 8MB + Wqkv 6MB (dead before
    // gemm<1> overwrites d_out with the final f32 result).
    u16* Xb   = (u16*)d_out;                          // [4096][1024] bf16
    u16* Wqkv = (u16*)d_out + (size_t)4 * 1048576;    // [3072][1024] bf16

    char* ws = (char*)d_ws;
    u16* Qb  = (u16*)(ws);                            // [B,H,S,64]  8MB
    u16* Kb  = (u16*)(ws + (size_t)8  * 1048576);     // [B,H,S,64]  8MB
    u16* VTb = (u16*)(ws + (size_t)16 * 1048576);     // [B,H,64,S]  8MB
    u16* Cat = (u16*)(ws + (size_t)24 * 1048576);     // [B,S,E]     8MB

    convert_all<<<3584, 256, 0, stream>>>(x, Wq, Wk, Wv, Xb, Wqkv);

    // QKV projection: M=4096, N=3072, K=1024 (Q pre-scaled by 0.125)
    dim3 g1(4096 / 128, 3072 / 128);
    gemm_bt<0><<<g1, 256, 0, stream>>>(Xb, Wqkv, nullptr, Qb, Kb, VTb, nullptr);

    // Attention
    dim3 g2(SEQ / 64, BATCH * NH);
    attn_fwd<<<g2, 256, 0, stream>>>(Qb, Kb, VTb, Cat);

    // Output projection: M=4096, N=1024, K=1024
    dim3 g3(4096 / 128, 1024 / 128);
    gemm_bt<1><<<g3, 256, 0, stream>>>(Cat, nullptr, Wo, nullptr, nullptr, nullptr, out);
}

// Round 4
// 132.502 us; speedup vs baseline: 1.7914x; 1.2709x over previous
//
#include <hip/hip_runtime.h>
#include <hip/hip_bf16.h>

typedef unsigned short u16;
typedef unsigned int u32;
typedef __attribute__((ext_vector_type(4))) float f32x4;
typedef __attribute__((ext_vector_type(8))) short short8;     // 8 bf16 MFMA frag
typedef __attribute__((ext_vector_type(8))) unsigned short u16x8;
typedef __attribute__((ext_vector_type(4))) unsigned short u16x4;
typedef __attribute__((ext_vector_type(2))) unsigned int u32x2;

// B=2, S=2048, E=1024, H=16, HD=64
#define BATCH 2
#define SEQ   2048
#define EMB   1024
#define NH    16
#define HD    64

__device__ inline u16 f2bf(float f) {
    unsigned u = __builtin_bit_cast(unsigned, f);
    unsigned r = u + 0x7FFFu + ((u >> 16) & 1u);   // RNE
    return (u16)(r >> 16);
}

__device__ inline void gload16(const void* g, void* l) {
    __builtin_amdgcn_global_load_lds(
        (const __attribute__((address_space(1))) unsigned int*)g,
        (__attribute__((address_space(3))) unsigned int*)l, 16, 0, 0);
}

// ---------------------------------------------------------------------------
// convert: x (4M f32) -> Xb bf16 ; Wq|Wk|Wv (3M f32) -> Wqkv bf16
// ---------------------------------------------------------------------------
__global__ __launch_bounds__(256) void convert_all(
    const float* __restrict__ x,
    const float* __restrict__ Wq, const float* __restrict__ Wk, const float* __restrict__ Wv,
    u16* __restrict__ Xb, u16* __restrict__ Wqkv)
{
    const long gidx = (long)blockIdx.x * 2048 + (long)threadIdx.x * 8;
    const float* src;
    u16* dst;
    if (gidx < 4194304L) {
        src = x + gidx; dst = Xb + gidx;
    } else {
        const long r = gidx - 4194304L;
        const int w = (int)(r >> 20);
        const long off = r & 1048575L;
        src = (w == 0 ? Wq : w == 1 ? Wk : Wv) + off;
        dst = Wqkv + r;
    }
    f32x4 a = *(const f32x4*)src;
    f32x4 b = *(const f32x4*)(src + 4);
    u16x8 o;
    #pragma unroll
    for (int j = 0; j < 4; ++j) { o[j] = f2bf(a[j]); o[4 + j] = f2bf(b[j]); }
    *(u16x8*)dst = o;
}

__global__ __launch_bounds__(256) void convert_wo(
    const float* __restrict__ Wo, u16* __restrict__ Wob)
{
    const long gidx = (long)blockIdx.x * 2048 + (long)threadIdx.x * 8;
    f32x4 a = *(const f32x4*)(Wo + gidx);
    f32x4 b = *(const f32x4*)(Wo + gidx + 4);
    u16x8 o;
    #pragma unroll
    for (int j = 0; j < 4; ++j) { o[j] = f2bf(a[j]); o[4 + j] = f2bf(b[j]); }
    *(u16x8*)(Wob + gidx) = o;
}

// ---------------------------------------------------------------------------
// GEMM C[m][n] = sum_k A[m][k] * B[n][k]   (K=1024, BK=64, 128x128 tile)
// A, B bf16 via global_load_lds with pre-swizzled source (st-style XOR swizzle
// on 16B chunks within each 128B row: LDS slot s of row r holds chunk s^(r&7)).
// MODE 0: epilogue scatters Q(x0.125),K -> [B,H,S,64], V -> VT [B,H,64,S].
// MODE 1: epilogue f32 out.
// ---------------------------------------------------------------------------
template<int MODE>
__global__ __launch_bounds__(256) void gemm_bt(
    const u16* __restrict__ A, const u16* __restrict__ Bb,
    u16* __restrict__ Qo, u16* __restrict__ Ko, u16* __restrict__ VTo,
    float* __restrict__ Fo)
{
    __shared__ u16 As[128 * 64];
    __shared__ u16 Bs[128 * 64];

    const int tid = threadIdx.x;
    const int m0 = blockIdx.x * 128;
    const int n0 = blockIdx.y * 128;

    const int lane = tid & 63;
    const int lr = lane & 15;
    const int lg = lane >> 4;
    const int wid = tid >> 6;
    const int wm = wid >> 1, wn = wid & 1;

    // gload geometry: issue covers 8 rows x 128B; lane -> row = base + (lane>>3),
    // LDS slot = lane&7; source chunk pre-swizzled: ((lane&7) ^ (lane>>3)) * 16B.
    const int grow = lane >> 3;
    const int gcolb = ((lane & 7) ^ grow) << 4;
    const int rswz = (lr & 7);

    f32x4 acc[4][4] = {};

    for (int kt = 0; kt < 16; ++kt) {
        const int k0b = kt * 128;          // byte offset in 2048B K-row
        __syncthreads();
        #pragma unroll
        for (int t = 0; t < 4; ++t) {
            const int row = (wid * 4 + t) * 8 + grow;
            gload16((const char*)A + (size_t)(m0 + row) * 2048 + k0b + gcolb,
                    (char*)As + (wid * 4 + t) * 1024);
            gload16((const char*)Bb + (size_t)(n0 + row) * 2048 + k0b + gcolb,
                    (char*)Bs + (wid * 4 + t) * 1024);
        }
        __syncthreads();

        #pragma unroll
        for (int kk = 0; kk < 2; ++kk) {
            short8 a[4], b[4];
            #pragma unroll
            for (int i = 0; i < 4; ++i)
                a[i] = *(const short8*)((const char*)As + (wm * 64 + i * 16 + lr) * 128
                                        + (((kk * 4 + lg) ^ rswz) << 4));
            #pragma unroll
            for (int i = 0; i < 4; ++i)
                b[i] = *(const short8*)((const char*)Bs + (wn * 64 + i * 16 + lr) * 128
                                        + (((kk * 4 + lg) ^ rswz) << 4));
            #pragma unroll
            for (int mi = 0; mi < 4; ++mi)
                #pragma unroll
                for (int ni = 0; ni < 4; ++ni)
                    acc[mi][ni] = __builtin_amdgcn_mfma_f32_16x16x32_bf16(a[mi], b[ni], acc[mi][ni], 0, 0, 0);
        }
    }

    // ---- epilogue: C col = lane&15, row = (lane>>4)*4 + i ----
    const int mb = m0 + wm * 64;
    const int nb = n0 + wn * 64;
    if (MODE == 0) {
        const int w = n0 >> 10;
        const float qs = (w == 0) ? 0.125f : 1.0f;
        #pragma unroll
        for (int mi = 0; mi < 4; ++mi) {
            #pragma unroll
            for (int ni = 0; ni < 4; ++ni) {
                const int m = mb + mi * 16 + lg * 4;
                const int nn = (nb + ni * 16 + lr) & 1023;
                const int h = nn >> 6, d = nn & 63;
                const int bb = m >> 11, s = m & 2047;
                const size_t bh = (size_t)(bb * NH + h);
                if (w == 2) {
                    u16x4 v;
                    #pragma unroll
                    for (int i = 0; i < 4; ++i) v[i] = f2bf(acc[mi][ni][i]);
                    *(u16x4*)&VTo[(bh * HD + d) * SEQ + s] = v;
                } else {
                    u16* P = (w == 0) ? Qo : Ko;
                    #pragma unroll
                    for (int i = 0; i < 4; ++i)
                        P[(bh * SEQ + s + i) * HD + d] = f2bf(acc[mi][ni][i] * qs);
                }
            }
        }
    } else {
        #pragma unroll
        for (int mi = 0; mi < 4; ++mi)
            #pragma unroll
            for (int ni = 0; ni < 4; ++ni) {
                const int m = mb + mi * 16 + lg * 4;
                const int n = nb + ni * 16 + lr;
                #pragma unroll
                for (int i = 0; i < 4; ++i)
                    Fo[(size_t)(m + i) * EMB + n] = acc[mi][ni][i];
            }
    }
}

// ---------------------------------------------------------------------------
// Flash attention, swapped-operand, 8 waves x 16 q-rows = 128 q/block.
// grid (S/128, B*H). ST[kv][q] = mfma(K, Q); lane owns q=lr.
// l computed by MFMA via constant ones-rows appended to V (accO[4]).
// Async-stage: tile t+1 global->reg issued under tile t compute.
// Defer-max: skip O-rescale when max growth <= 8.
// ---------------------------------------------------------------------------
__global__ __launch_bounds__(512) void attn_fwd(
    const u16* __restrict__ Q, const u16* __restrict__ K,
    const u16* __restrict__ VT, u16* __restrict__ Cat)
{
    __shared__ u16 Ks[64 * 64];        // [kv][e], 128B rows, XOR-swizzled
    __shared__ u16 Vs[80 * 64];        // [d][kv] rows 0..63; rows 64..79 = 1.0
    __shared__ u16 PT[8][16 * 72];     // per-wave P [q][kv], pad-72

    const int tid = threadIdx.x;
    const int lane = tid & 63;
    const int lr = lane & 15;
    const int lg = lane >> 4;
    const int wid = tid >> 6;
    const int qt = blockIdx.x;
    const int bh = blockIdx.y;
    const int b = bh >> 4, h = bh & 15;

    // ones rows for the l-column (V rows 64..79)
    if (tid < 128) {
        const int row = 64 + (tid >> 3), sl = tid & 7;
        u16x8 ones;
        #pragma unroll
        for (int j = 0; j < 8; ++j) ones[j] = 0x3F80;
        *(u16x8*)((char*)Vs + row * 128 + ((sl ^ (row & 7)) << 4)) = ones;
    }

    // Q fragments (B operand): col = lr <-> q, k = kk*32 + lg*8 + j
    const u16* Qg = Q + ((size_t)bh * SEQ + qt * 128 + wid * 16 + lr) * HD;
    short8 qf[2];
    qf[0] = *(const short8*)(Qg + lg * 8);
    qf[1] = *(const short8*)(Qg + 32 + lg * 8);

    float m = -1e30f;
    f32x4 accO[5] = {};                // [0..3]=O^T d-blocks, [4]=l (ones rows)

    const u16* Kg = K + (size_t)bh * SEQ * HD;
    const u16* Vg = VT + (size_t)bh * HD * SEQ;

    // staging coords: 512 threads, 1x16B K + 1x16B V each per tile
    const int srow = tid >> 3;         // 0..63
    const int scol = tid & 7;
    const int sswz = (scol ^ (srow & 7)) << 4;
    const u16* kp = Kg + (size_t)srow * HD + scol * 8;
    const u16* vp = Vg + (size_t)srow * SEQ + scol * 8;

    u16x8 kreg = *(const u16x8*)kp;    // tile 0
    u16x8 vreg = *(const u16x8*)vp;

    for (int nt = 0; nt < SEQ / 64; ++nt) {
        __syncthreads();               // prev readers done; LDS writable
        *(u16x8*)((char*)Ks + srow * 128 + sswz) = kreg;
        *(u16x8*)((char*)Vs + srow * 128 + sswz) = vreg;
        if (nt + 1 < SEQ / 64) {       // issue next tile under this tile's compute
            kreg = *(const u16x8*)(kp + (size_t)(nt + 1) * 64 * HD);
            vreg = *(const u16x8*)(vp + (nt + 1) * 64);
        }
        __syncthreads();               // tile visible

        // ---- ST = K Q^T : lane owns q=lr; kv = c*16 + lg*4 + i ----
        f32x4 st[4] = {};
        #pragma unroll
        for (int kk = 0; kk < 2; ++kk) {
            const short8 qv = qf[kk];
            #pragma unroll
            for (int c = 0; c < 4; ++c) {
                const short8 kf = *(const short8*)((const char*)Ks + (c * 16 + lr) * 128
                                                   + (((kk * 4 + lg) ^ (lr & 7)) << 4));
                st[c] = __builtin_amdgcn_mfma_f32_16x16x32_bf16(kf, qv, st[c], 0, 0, 0);
            }
        }

        // ---- online softmax, defer-max ----
        float mx = fmaxf(
            fmaxf(fmaxf(fmaxf(st[0][0], st[0][1]), fmaxf(st[0][2], st[0][3])),
                  fmaxf(fmaxf(st[1][0], st[1][1]), fmaxf(st[1][2], st[1][3]))),
            fmaxf(fmaxf(fmaxf(st[2][0], st[2][1]), fmaxf(st[2][2], st[2][3])),
                  fmaxf(fmaxf(st[3][0], st[3][1]), fmaxf(st[3][2], st[3][3]))));
        mx = fmaxf(mx, __shfl_xor(mx, 16));
        mx = fmaxf(mx, __shfl_xor(mx, 32));
        if (!__all(mx - m <= 8.f)) {
            const float nm = fmaxf(m, mx);
            const float corr = __expf(m - nm);
            m = nm;
            #pragma unroll
            for (int dc = 0; dc < 5; ++dc)
                accO[dc] *= corr;
        }
        #pragma unroll
        for (int c = 0; c < 4; ++c)
            #pragma unroll
            for (int i = 0; i < 4; ++i)
                st[c][i] = __expf(st[c][i] - m);

        // ---- P pack -> PT[q=lr][kv] ----
        #pragma unroll
        for (int c = 0; c < 4; ++c) {
            u32 w0, w1;
            asm("v_cvt_pk_bf16_f32 %0, %1, %2" : "=v"(w0) : "v"(st[c][0]), "v"(st[c][1]));
            asm("v_cvt_pk_bf16_f32 %0, %1, %2" : "=v"(w1) : "v"(st[c][2]), "v"(st[c][3]));
            u32x2 pk; pk[0] = w0; pk[1] = w1;
            *(u32x2*)&PT[wid][lr * 72 + c * 16 + lg * 4] = pk;
        }
        asm volatile("s_waitcnt lgkmcnt(0)" ::: "memory");
        __builtin_amdgcn_sched_barrier(0);

        // ---- O^T += V^T P (dc=4 -> ones rows accumulate l) ----
        #pragma unroll
        for (int kk = 0; kk < 2; ++kk) {
            const short8 pf = *(const short8*)&PT[wid][lr * 72 + kk * 32 + lg * 8];
            #pragma unroll
            for (int dc = 0; dc < 5; ++dc) {
                const short8 vf = *(const short8*)((const char*)Vs + (dc * 16 + lr) * 128
                                                   + (((kk * 4 + lg) ^ (lr & 7)) << 4));
                accO[dc] = __builtin_amdgcn_mfma_f32_16x16x32_bf16(vf, pf, accO[dc], 0, 0, 0);
            }
        }
    }

    // ---- epilogue: lane q = lr; d = dc*16 + lg*4 + i ----
    const float invl = 1.f / accO[4][0];
    const int qs = qt * 128 + wid * 16 + lr;
    u16* ob = Cat + (size_t)b * SEQ * EMB + (size_t)qs * EMB + h * HD;
    #pragma unroll
    for (int dc = 0; dc < 4; ++dc) {
        u16x4 o;
        #pragma unroll
        for (int i = 0; i < 4; ++i) o[i] = f2bf(accO[dc][i] * invl);
        *(u16x4*)&ob[dc * 16 + lg * 4] = o;
    }
}

// ---------------------------------------------------------------------------
extern "C" void kernel_launch(void* const* d_in, const int* in_sizes, int n_in,
                              void* d_out, int out_size, void* d_ws, size_t ws_size,
                              hipStream_t stream) {
    const float* x  = (const float*)d_in[0];
    const float* Wq = (const float*)d_in[1];
    const float* Wk = (const float*)d_in[2];
    const float* Wv = (const float*)d_in[3];
    const float* Wo = (const float*)d_in[4];
    float* out = (float*)d_out;

    // d_out (16MB) doubles as bf16 staging for Xb+Wqkv (dead before gemm<1>
    // overwrites d_out with the final f32 result).
    u16* Xb   = (u16*)d_out;                          // [4096][1024] bf16
    u16* Wqkv = (u16*)d_out + (size_t)4 * 1048576;    // [3072][1024] bf16

    char* ws = (char*)d_ws;
    u16* Qb  = (u16*)(ws);                            // [B,H,S,64]  8MB
    u16* Kb  = (u16*)(ws + (size_t)8  * 1048576);     // [B,H,S,64]  8MB
    u16* VTb = (u16*)(ws + (size_t)16 * 1048576);     // [B,H,64,S]  8MB
    u16* Cat = (u16*)(ws + (size_t)24 * 1048576);     // [B,S,E]     8MB
    u16* Wob = Qb;                                    // Qb dead after attn

    convert_all<<<3584, 256, 0, stream>>>(x, Wq, Wk, Wv, Xb, Wqkv);

    // QKV projection: M=4096, N=3072, K=1024 (Q pre-scaled by 0.125)
    dim3 g1(4096 / 128, 3072 / 128);
    gemm_bt<0><<<g1, 256, 0, stream>>>(Xb, Wqkv, Qb, Kb, VTb, nullptr);

    // Attention (128 q-rows/block, 8 waves)
    dim3 g2(SEQ / 128, BATCH * NH);
    attn_fwd<<<g2, 512, 0, stream>>>(Qb, Kb, VTb, Cat);

    // Wo -> bf16 into Qb region, then output projection M=4096,N=1024,K=1024
    convert_wo<<<512, 256, 0, stream>>>(Wo, Wob);
    dim3 g3(4096 / 128, 1024 / 128);
    gemm_bt<1><<<g3, 256, 0, stream>>>(Cat, Wob, nullptr, nullptr, nullptr, out);
}

// Round 5
// 130.449 us; speedup vs baseline: 1.8196x; 1.0157x over previous
//
#include <hip/hip_runtime.h>
#include <hip/hip_bf16.h>

typedef unsigned short u16;
typedef unsigned int u32;
typedef __attribute__((ext_vector_type(4))) float f32x4;
typedef __attribute__((ext_vector_type(8))) short short8;     // 8 bf16 MFMA frag
typedef __attribute__((ext_vector_type(8))) unsigned short u16x8;
typedef __attribute__((ext_vector_type(4))) unsigned short u16x4;
typedef __attribute__((ext_vector_type(2))) unsigned int u32x2;

// B=2, S=2048, E=1024, H=16, HD=64
#define BATCH 2
#define SEQ   2048
#define EMB   1024
#define NH    16
#define HD    64

__device__ inline u16 f2bf(float f) {
    unsigned u = __builtin_bit_cast(unsigned, f);
    unsigned r = u + 0x7FFFu + ((u >> 16) & 1u);   // RNE
    return (u16)(r >> 16);
}

__device__ inline float fexp2(float x) {
    float r;
    asm("v_exp_f32 %0, %1" : "=v"(r) : "v"(x));
    return r;
}

__device__ inline void gload16(const void* g, void* l) {
    __builtin_amdgcn_global_load_lds(
        (const __attribute__((address_space(1))) unsigned int*)g,
        (__attribute__((address_space(3))) unsigned int*)l, 16, 0, 0);
}

// ---------------------------------------------------------------------------
// convert: x (4M f32) -> Xb bf16 ; Wq|Wk|Wv (3M f32) -> Wqkv bf16
// ---------------------------------------------------------------------------
__global__ __launch_bounds__(256) void convert_all(
    const float* __restrict__ x,
    const float* __restrict__ Wq, const float* __restrict__ Wk, const float* __restrict__ Wv,
    u16* __restrict__ Xb, u16* __restrict__ Wqkv)
{
    const long gidx = (long)blockIdx.x * 2048 + (long)threadIdx.x * 8;
    const float* src;
    u16* dst;
    if (gidx < 4194304L) {
        src = x + gidx; dst = Xb + gidx;
    } else {
        const long r = gidx - 4194304L;
        const int w = (int)(r >> 20);
        const long off = r & 1048575L;
        src = (w == 0 ? Wq : w == 1 ? Wk : Wv) + off;
        dst = Wqkv + r;
    }
    f32x4 a = *(const f32x4*)src;
    f32x4 b = *(const f32x4*)(src + 4);
    u16x8 o;
    #pragma unroll
    for (int j = 0; j < 4; ++j) { o[j] = f2bf(a[j]); o[4 + j] = f2bf(b[j]); }
    *(u16x8*)dst = o;
}

__global__ __launch_bounds__(256) void convert_wo(
    const float* __restrict__ Wo, u16* __restrict__ Wob)
{
    const long gidx = (long)blockIdx.x * 2048 + (long)threadIdx.x * 8;
    f32x4 a = *(const f32x4*)(Wo + gidx);
    f32x4 b = *(const f32x4*)(Wo + gidx + 4);
    u16x8 o;
    #pragma unroll
    for (int j = 0; j < 4; ++j) { o[j] = f2bf(a[j]); o[4 + j] = f2bf(b[j]); }
    *(u16x8*)(Wob + gidx) = o;
}

// ---------------------------------------------------------------------------
// GEMM C[m][n] = sum_k A[m][k] * B[n][k]   (K=1024, BK=64, 128x128 tile)
// 2-phase pipeline: double-buffered LDS, one barrier per K-step, gloads for
// step t+1 issued right after the barrier (drained by next barrier's vmcnt).
// XOR-swizzled 16B chunks within 128B rows (pre-swizzled global source).
// MODE 0: epilogue scatters Q(x0.125*log2e),K -> [B,H,S,64], V -> VT.
// MODE 1: epilogue f32 out.
// ---------------------------------------------------------------------------
template<int MODE>
__global__ __launch_bounds__(256) void gemm_bt(
    const u16* __restrict__ A, const u16* __restrict__ Bb,
    u16* __restrict__ Qo, u16* __restrict__ Ko, u16* __restrict__ VTo,
    float* __restrict__ Fo)
{
    __shared__ u16 As[2][128 * 64];
    __shared__ u16 Bs[2][128 * 64];

    const int tid = threadIdx.x;
    const int m0 = blockIdx.x * 128;
    const int n0 = blockIdx.y * 128;

    const int lane = tid & 63;
    const int lr = lane & 15;
    const int lg = lane >> 4;
    const int wid = tid >> 6;
    const int wm = wid >> 1, wn = wid & 1;

    // gload geometry: issue covers 8 rows x 128B; lane -> row = base+(lane>>3),
    // LDS slot = lane&7; source chunk pre-swizzled: ((lane&7)^(lane>>3))*16B.
    const int grow = lane >> 3;
    const int gcolb = ((lane & 7) ^ grow) << 4;
    const int rswz = (lr & 7);

    f32x4 acc[4][4] = {};

    auto issue = [&](int kt, int buf) {
        const int k0b = kt * 128;          // byte offset in 2048B K-row
        #pragma unroll
        for (int t = 0; t < 4; ++t) {
            const int row = (wid * 4 + t) * 8 + grow;
            gload16((const char*)A + (size_t)(m0 + row) * 2048 + k0b + gcolb,
                    (char*)As[buf] + (wid * 4 + t) * 1024);
            gload16((const char*)Bb + (size_t)(n0 + row) * 2048 + k0b + gcolb,
                    (char*)Bs[buf] + (wid * 4 + t) * 1024);
        }
    };

    issue(0, 0);

    for (int kt = 0; kt < 16; ++kt) {
        const int cur = kt & 1;
        __syncthreads();                   // drains vmcnt(0): buf[cur] ready
        if (kt + 1 < 16) issue(kt + 1, cur ^ 1);

        const u16* Ac = As[cur];
        const u16* Bc = Bs[cur];
        #pragma unroll
        for (int kk = 0; kk < 2; ++kk) {
            short8 a[4], b[4];
            #pragma unroll
            for (int i = 0; i < 4; ++i)
                a[i] = *(const short8*)((const char*)Ac + (wm * 64 + i * 16 + lr) * 128
                                        + (((kk * 4 + lg) ^ rswz) << 4));
            #pragma unroll
            for (int i = 0; i < 4; ++i)
                b[i] = *(const short8*)((const char*)Bc + (wn * 64 + i * 16 + lr) * 128
                                        + (((kk * 4 + lg) ^ rswz) << 4));
            #pragma unroll
            for (int mi = 0; mi < 4; ++mi)
                #pragma unroll
                for (int ni = 0; ni < 4; ++ni)
                    acc[mi][ni] = __builtin_amdgcn_mfma_f32_16x16x32_bf16(a[mi], b[ni], acc[mi][ni], 0, 0, 0);
        }
    }

    // ---- epilogue: C col = lane&15, row = (lane>>4)*4 + i ----
    const int mb = m0 + wm * 64;
    const int nb = n0 + wn * 64;
    if (MODE == 0) {
        const int w = n0 >> 10;
        const float qs = (w == 0) ? 0.125f * 1.44269504f : 1.0f;   // Q in log2 domain
        #pragma unroll
        for (int mi = 0; mi < 4; ++mi) {
            #pragma unroll
            for (int ni = 0; ni < 4; ++ni) {
                const int m = mb + mi * 16 + lg * 4;
                const int nn = (nb + ni * 16 + lr) & 1023;
                const int h = nn >> 6, d = nn & 63;
                const int bb = m >> 11, s = m & 2047;
                const size_t bh = (size_t)(bb * NH + h);
                if (w == 2) {
                    u16x4 v;
                    #pragma unroll
                    for (int i = 0; i < 4; ++i) v[i] = f2bf(acc[mi][ni][i]);
                    *(u16x4*)&VTo[(bh * HD + d) * SEQ + s] = v;
                } else {
                    u16* P = (w == 0) ? Qo : Ko;
                    #pragma unroll
                    for (int i = 0; i < 4; ++i)
                        P[(bh * SEQ + s + i) * HD + d] = f2bf(acc[mi][ni][i] * qs);
                }
            }
        }
    } else {
        #pragma unroll
        for (int mi = 0; mi < 4; ++mi)
            #pragma unroll
            for (int ni = 0; ni < 4; ++ni) {
                const int m = mb + mi * 16 + lg * 4;
                const int n = nb + ni * 16 + lr;
                #pragma unroll
                for (int i = 0; i < 4; ++i)
                    Fo[(size_t)(m + i) * EMB + n] = acc[mi][ni][i];
            }
    }
}

// ---------------------------------------------------------------------------
// Flash attention, swapped-operand, 8 waves x 16 q-rows = 128 q/block.
// grid (S/128, B*H). ST[kv][q] = mfma(K, Q); lane owns q=lr. Scores arrive in
// log2 domain (Q pre-scaled by 0.125*log2e) -> raw v_exp_f32.
// l computed by MFMA via constant ones-rows appended to V (accO[4]).
// 2-phase pipeline: K/V double-buffered via global_load_lds (pre-swizzled
// source), one barrier per tile, next-tile loads issued under compute.
// Defer-max: skip O-rescale while max growth <= 11.5 (log2 units ~ e^8).
// ---------------------------------------------------------------------------
__global__ __launch_bounds__(512) void attn_fwd(
    const u16* __restrict__ Q, const u16* __restrict__ K,
    const u16* __restrict__ VT, u16* __restrict__ Cat)
{
    __shared__ u16 Ks[2][64 * 64];     // [kv][e], 128B rows, XOR-swizzled
    __shared__ u16 Vs[2][80 * 64];     // [d][kv] rows 0..63; rows 64..79 = 1.0
    __shared__ u16 PT[8][16 * 72];     // per-wave P [q][kv], pad-72

    const int tid = threadIdx.x;
    const int lane = tid & 63;
    const int lr = lane & 15;
    const int lg = lane >> 4;
    const int wid = tid >> 6;
    const int qt = blockIdx.x;
    const int bh = blockIdx.y;
    const int b = bh >> 4, h = bh & 15;

    // ones rows for the l-column (V rows 64..79, both buffers)
    if (tid < 128) {
        const int row = 64 + (tid >> 3), sl = tid & 7;
        u16x8 ones;
        #pragma unroll
        for (int j = 0; j < 8; ++j) ones[j] = 0x3F80;
        *(u16x8*)((char*)Vs[0] + row * 128 + ((sl ^ (row & 7)) << 4)) = ones;
        *(u16x8*)((char*)Vs[1] + row * 128 + ((sl ^ (row & 7)) << 4)) = ones;
    }

    // Q fragments (B operand): col = lr <-> q, k = kk*32 + lg*8 + j
    const u16* Qg = Q + ((size_t)bh * SEQ + qt * 128 + wid * 16 + lr) * HD;
    short8 qf[2];
    qf[0] = *(const short8*)(Qg + lg * 8);
    qf[1] = *(const short8*)(Qg + 32 + lg * 8);

    float m = -1e30f;
    f32x4 accO[5] = {};                // [0..3]=O^T d-blocks, [4]=l (ones rows)

    const u16* Kg = K + (size_t)bh * SEQ * HD;
    const u16* Vg = VT + (size_t)bh * HD * SEQ;

    // gload staging: 8 waves; wave w stages 1KB of K (rows w*8..w*8+7) and
    // 1KB of V; lane -> row offset lane>>3, chunk lane&7, pre-swizzled source.
    const int srow = lane >> 3;
    const int schunk = ((lane & 7) ^ srow) << 4;    // source byte offset in row

    auto issueKV = [&](int nt, int buf) {
        const int kv0 = nt * 64;
        const int krow = wid * 8 + srow;
        gload16((const char*)Kg + (size_t)(kv0 + krow) * 128 + schunk,
                (char*)Ks[buf] + wid * 1024);
        gload16((const char*)Vg + (size_t)krow * (SEQ * 2) + kv0 * 2 + schunk,
                (char*)Vs[buf] + wid * 1024);
    };

    issueKV(0, 0);

    for (int nt = 0; nt < SEQ / 64; ++nt) {
        const int cur = nt & 1;
        __syncthreads();               // drains vmcnt: buf[cur] ready
        if (nt + 1 < SEQ / 64) issueKV(nt + 1, cur ^ 1);

        // ---- ST = K Q^T : lane owns q=lr; kv = c*16 + lg*4 + i ----
        f32x4 st[4] = {};
        #pragma unroll
        for (int kk = 0; kk < 2; ++kk) {
            const short8 qv = qf[kk];
            #pragma unroll
            for (int c = 0; c < 4; ++c) {
                const short8 kf = *(const short8*)((const char*)Ks[cur] + (c * 16 + lr) * 128
                                                   + (((kk * 4 + lg) ^ (lr & 7)) << 4));
                st[c] = __builtin_amdgcn_mfma_f32_16x16x32_bf16(kf, qv, st[c], 0, 0, 0);
            }
        }

        // ---- online softmax (log2 domain), defer-max ----
        float mx = fmaxf(
            fmaxf(fmaxf(fmaxf(st[0][0], st[0][1]), fmaxf(st[0][2], st[0][3])),
                  fmaxf(fmaxf(st[1][0], st[1][1]), fmaxf(st[1][2], st[1][3]))),
            fmaxf(fmaxf(fmaxf(st[2][0], st[2][1]), fmaxf(st[2][2], st[2][3])),
                  fmaxf(fmaxf(st[3][0], st[3][1]), fmaxf(st[3][2], st[3][3]))));
        mx = fmaxf(mx, __shfl_xor(mx, 16));
        mx = fmaxf(mx, __shfl_xor(mx, 32));
        if (!__all(mx - m <= 11.5f)) {
            const float nm = fmaxf(m, mx);
            const float corr = fexp2(m - nm);
            m = nm;
            #pragma unroll
            for (int dc = 0; dc < 5; ++dc)
                accO[dc] *= corr;
        }
        #pragma unroll
        for (int c = 0; c < 4; ++c)
            #pragma unroll
            for (int i = 0; i < 4; ++i)
                st[c][i] = fexp2(st[c][i] - m);

        // ---- P pack -> PT[q=lr][kv] ----
        #pragma unroll
        for (int c = 0; c < 4; ++c) {
            u32 w0, w1;
            asm("v_cvt_pk_bf16_f32 %0, %1, %2" : "=v"(w0) : "v"(st[c][0]), "v"(st[c][1]));
            asm("v_cvt_pk_bf16_f32 %0, %1, %2" : "=v"(w1) : "v"(st[c][2]), "v"(st[c][3]));
            u32x2 pk; pk[0] = w0; pk[1] = w1;
            *(u32x2*)&PT[wid][lr * 72 + c * 16 + lg * 4] = pk;
        }
        asm volatile("s_waitcnt lgkmcnt(0)" ::: "memory");
        __builtin_amdgcn_sched_barrier(0);

        // ---- O^T += V^T P (dc=4 -> ones rows accumulate l) ----
        #pragma unroll
        for (int kk = 0; kk < 2; ++kk) {
            const short8 pf = *(const short8*)&PT[wid][lr * 72 + kk * 32 + lg * 8];
            #pragma unroll
            for (int dc = 0; dc < 5; ++dc) {
                const short8 vf = *(const short8*)((const char*)Vs[cur] + (dc * 16 + lr) * 128
                                                   + (((kk * 4 + lg) ^ (lr & 7)) << 4));
                accO[dc] = __builtin_amdgcn_mfma_f32_16x16x32_bf16(vf, pf, accO[dc], 0, 0, 0);
            }
        }
    }

    // ---- epilogue: lane q = lr; d = dc*16 + lg*4 + i ----
    const float invl = 1.f / accO[4][0];
    const int qs = qt * 128 + wid * 16 + lr;
    u16* ob = Cat + (size_t)b * SEQ * EMB + (size_t)qs * EMB + h * HD;
    #pragma unroll
    for (int dc = 0; dc < 4; ++dc) {
        u16x4 o;
        #pragma unroll
        for (int i = 0; i < 4; ++i) o[i] = f2bf(accO[dc][i] * invl);
        *(u16x4*)&ob[dc * 16 + lg * 4] = o;
    }
}

// ---------------------------------------------------------------------------
extern "C" void kernel_launch(void* const* d_in, const int* in_sizes, int n_in,
                              void* d_out, int out_size, void* d_ws, size_t ws_size,
                              hipStream_t stream) {
    const float* x  = (const float*)d_in[0];
    const float* Wq = (const float*)d_in[1];
    const float* Wk = (const float*)d_in[2];
    const float* Wv = (const float*)d_in[3];
    const float* Wo = (const float*)d_in[4];
    float* out = (float*)d_out;

    // d_out (16MB) doubles as bf16 staging for Xb+Wqkv (dead before gemm<1>
    // overwrites d_out with the final f32 result).
    u16* Xb   = (u16*)d_out;                          // [4096][1024] bf16
    u16* Wqkv = (u16*)d_out + (size_t)4 * 1048576;    // [3072][1024] bf16

    char* ws = (char*)d_ws;
    u16* Qb  = (u16*)(ws);                            // [B,H,S,64]  8MB
    u16* Kb  = (u16*)(ws + (size_t)8  * 1048576);     // [B,H,S,64]  8MB
    u16* VTb = (u16*)(ws + (size_t)16 * 1048576);     // [B,H,64,S]  8MB
    u16* Cat = (u16*)(ws + (size_t)24 * 1048576);     // [B,S,E]     8MB
    u16* Wob = Qb;                                    // Qb dead after attn

    convert_all<<<3584, 256, 0, stream>>>(x, Wq, Wk, Wv, Xb, Wqkv);

    // QKV projection: M=4096, N=3072, K=1024 (Q pre-scaled by 0.125*log2e)
    dim3 g1(4096 / 128, 3072 / 128);
    gemm_bt<0><<<g1, 256, 0, stream>>>(Xb, Wqkv, Qb, Kb, VTb, nullptr);

    // Attention (128 q-rows/block, 8 waves)
    dim3 g2(SEQ / 128, BATCH * NH);
    attn_fwd<<<g2, 512, 0, stream>>>(Qb, Kb, VTb, Cat);

    // Wo -> bf16 into Qb region, then output projection M=4096,N=1024,K=1024
    convert_wo<<<512, 256, 0, stream>>>(Wo, Wob);
    dim3 g3(4096 / 128, 1024 / 128);
    gemm_bt<1><<<g3, 256, 0, stream>>>(Cat, Wob, nullptr, nullptr, nullptr, out);
}

// Round 6
// 125.969 us; speedup vs baseline: 1.8843x; 1.0356x over previous
//
#include <hip/hip_runtime.h>
#include <hip/hip_bf16.h>

typedef unsigned short u16;
typedef unsigned int u32;
typedef __attribute__((ext_vector_type(4))) float f32x4;
typedef __attribute__((ext_vector_type(8))) short short8;     // 8 bf16 MFMA frag
typedef __attribute__((ext_vector_type(8))) unsigned short u16x8;
typedef __attribute__((ext_vector_type(4))) unsigned short u16x4;
typedef __attribute__((ext_vector_type(2))) unsigned int u32x2;

// B=2, S=2048, E=1024, H=16, HD=64
#define BATCH 2
#define SEQ   2048
#define EMB   1024
#define NH    16
#define HD    64

__device__ inline u16 f2bf(float f) {
    unsigned u = __builtin_bit_cast(unsigned, f);
    unsigned r = u + 0x7FFFu + ((u >> 16) & 1u);   // RNE
    return (u16)(r >> 16);
}

__device__ inline float fexp2(float x) {
    float r;
    asm("v_exp_f32 %0, %1" : "=v"(r) : "v"(x));
    return r;
}

__device__ inline void gload16(const void* g, void* l) {
    __builtin_amdgcn_global_load_lds(
        (const __attribute__((address_space(1))) unsigned int*)g,
        (__attribute__((address_space(3))) unsigned int*)l, 16, 0, 0);
}

// ---------------------------------------------------------------------------
// convert: x (4M f32) -> Xb bf16 ; Wq|Wk|Wv (3M f32) -> Wqkv bf16
// ---------------------------------------------------------------------------
__global__ __launch_bounds__(256) void convert_all(
    const float* __restrict__ x,
    const float* __restrict__ Wq, const float* __restrict__ Wk, const float* __restrict__ Wv,
    u16* __restrict__ Xb, u16* __restrict__ Wqkv)
{
    const long gidx = (long)blockIdx.x * 2048 + (long)threadIdx.x * 8;
    const float* src;
    u16* dst;
    if (gidx < 4194304L) {
        src = x + gidx; dst = Xb + gidx;
    } else {
        const long r = gidx - 4194304L;
        const int w = (int)(r >> 20);
        const long off = r & 1048575L;
        src = (w == 0 ? Wq : w == 1 ? Wk : Wv) + off;
        dst = Wqkv + r;
    }
    f32x4 a = *(const f32x4*)src;
    f32x4 b = *(const f32x4*)(src + 4);
    u16x8 o;
    #pragma unroll
    for (int j = 0; j < 4; ++j) { o[j] = f2bf(a[j]); o[4 + j] = f2bf(b[j]); }
    *(u16x8*)dst = o;
}

__global__ __launch_bounds__(256) void convert_wo(
    const float* __restrict__ Wo, u16* __restrict__ Wob)
{
    const long gidx = (long)blockIdx.x * 2048 + (long)threadIdx.x * 8;
    f32x4 a = *(const f32x4*)(Wo + gidx);
    f32x4 b = *(const f32x4*)(Wo + gidx + 4);
    u16x8 o;
    #pragma unroll
    for (int j = 0; j < 4; ++j) { o[j] = f2bf(a[j]); o[4 + j] = f2bf(b[j]); }
    *(u16x8*)(Wob + gidx) = o;
}

// ---------------------------------------------------------------------------
// gemm256: QKV projection, 256x256 tile, BK=64, 8 waves (2Mx4N), 512 thr.
// T3+T4: 2-deep prefetch via global_load_lds; counted s_waitcnt vmcnt(8) +
// RAW s_barrier (no implicit vmcnt(0) drain) -> loads stay in flight across
// barriers. 4 compute phases per K-tile, 16 MFMA each, setprio-wrapped.
// LDS 128KB: A[2][256][64] + B[2][256][64] bf16, XOR-swizzled 16B chunks
// (pre-swizzled global source; swizzle key = row&7).
// Epilogue: Q(x0.125*log2e),K -> [B,H,S,64]; V -> VT [B,H,64,S].
// ---------------------------------------------------------------------------
__global__ __launch_bounds__(512, 2) void gemm256(
    const u16* __restrict__ A, const u16* __restrict__ Bb,
    u16* __restrict__ Qo, u16* __restrict__ Ko, u16* __restrict__ VTo)
{
    __shared__ u16 As[2][256 * 64];
    __shared__ u16 Bs[2][256 * 64];

    const int tid = threadIdx.x;
    const int lane = tid & 63;
    const int wid = tid >> 6;          // 0..7
    const int lr = lane & 15;
    const int lg = lane >> 4;
    const int wr = wid >> 2;           // 0..1 -> M offset wr*128
    const int wc = wid & 3;            // 0..3 -> N offset wc*64
    const int m0 = blockIdx.x * 256;
    const int n0 = blockIdx.y * 256;

    // stage geometry: 8 gload insts per thread per K-tile (4 A + 4 B).
    // inst i: wave w writes LDS rows i*64 + w*8 + (lane>>3), chunk lane&7;
    // source chunk pre-swizzled by row&7 = lane>>3.
    const int grow = lane >> 3;
    const int schunk = ((lane & 7) ^ grow) << 4;

    auto issueTile = [&](int kt, int buf) {
        const int k0b = kt * 128;      // byte offset in 2048B K-row
        #pragma unroll
        for (int i = 0; i < 4; ++i) {
            const int row = i * 64 + wid * 8 + grow;
            gload16((const char*)A + (size_t)(m0 + row) * 2048 + k0b + schunk,
                    (char*)As[buf] + i * 8192 + wid * 1024);
            gload16((const char*)Bb + (size_t)(n0 + row) * 2048 + k0b + schunk,
                    (char*)Bs[buf] + i * 8192 + wid * 1024);
        }
    };

    issueTile(0, 0);
    issueTile(1, 1);

    f32x4 acc[8][4] = {};
    const int rsw = (lr & 7);

    for (int t = 0; t < 16; ++t) {
        if (t < 15) { asm volatile("s_waitcnt vmcnt(8)" ::: "memory"); }
        else        { asm volatile("s_waitcnt vmcnt(0)" ::: "memory"); }
        __builtin_amdgcn_sched_barrier(0);
        __builtin_amdgcn_s_barrier();
        __builtin_amdgcn_sched_barrier(0);

        const u16* Ac = As[t & 1];
        const u16* Bc = Bs[t & 1];

        short8 a[4][2], b0[2][2], b1[2][2];

        // ---- phase 1: A-half 0 (fi 0-3) x B-half 0 (fj 0-1) ----
        #pragma unroll
        for (int fi = 0; fi < 4; ++fi)
            #pragma unroll
            for (int ks = 0; ks < 2; ++ks)
                a[fi][ks] = *(const short8*)((const char*)Ac + (wr * 128 + fi * 16 + lr) * 128
                                             + (((ks * 4 + lg) ^ rsw) << 4));
        #pragma unroll
        for (int fj = 0; fj < 2; ++fj)
            #pragma unroll
            for (int ks = 0; ks < 2; ++ks)
                b0[fj][ks] = *(const short8*)((const char*)Bc + (wc * 64 + fj * 16 + lr) * 128
                                              + (((ks * 4 + lg) ^ rsw) << 4));
        __builtin_amdgcn_s_setprio(1);
        #pragma unroll
        for (int fi = 0; fi < 4; ++fi)
            #pragma unroll
            for (int fj = 0; fj < 2; ++fj)
                #pragma unroll
                for (int ks = 0; ks < 2; ++ks)
                    acc[fi][fj] = __builtin_amdgcn_mfma_f32_16x16x32_bf16(a[fi][ks], b0[fj][ks], acc[fi][fj], 0, 0, 0);
        __builtin_amdgcn_s_setprio(0);

        // ---- phase 2: A-half 0 x B-half 1 (fj 2-3) ----
        #pragma unroll
        for (int fj = 0; fj < 2; ++fj)
            #pragma unroll
            for (int ks = 0; ks < 2; ++ks)
                b1[fj][ks] = *(const short8*)((const char*)Bc + (wc * 64 + (fj + 2) * 16 + lr) * 128
                                              + (((ks * 4 + lg) ^ rsw) << 4));
        __builtin_amdgcn_s_setprio(1);
        #pragma unroll
        for (int fi = 0; fi < 4; ++fi)
            #pragma unroll
            for (int fj = 0; fj < 2; ++fj)
                #pragma unroll
                for (int ks = 0; ks < 2; ++ks)
                    acc[fi][fj + 2] = __builtin_amdgcn_mfma_f32_16x16x32_bf16(a[fi][ks], b1[fj][ks], acc[fi][fj + 2], 0, 0, 0);
        __builtin_amdgcn_s_setprio(0);

        // ---- phase 3: A-half 1 (fi 4-7) x B-half 1 ----
        #pragma unroll
        for (int fi = 0; fi < 4; ++fi)
            #pragma unroll
            for (int ks = 0; ks < 2; ++ks)
                a[fi][ks] = *(const short8*)((const char*)Ac + (wr * 128 + (fi + 4) * 16 + lr) * 128
                                             + (((ks * 4 + lg) ^ rsw) << 4));
        __builtin_amdgcn_s_setprio(1);
        #pragma unroll
        for (int fi = 0; fi < 4; ++fi)
            #pragma unroll
            for (int fj = 0; fj < 2; ++fj)
                #pragma unroll
                for (int ks = 0; ks < 2; ++ks)
                    acc[fi + 4][fj + 2] = __builtin_amdgcn_mfma_f32_16x16x32_bf16(a[fi][ks], b1[fj][ks], acc[fi + 4][fj + 2], 0, 0, 0);
        __builtin_amdgcn_s_setprio(0);

        // ---- phase 4: A-half 1 x B-half 0 (no reads) ----
        __builtin_amdgcn_s_setprio(1);
        #pragma unroll
        for (int fi = 0; fi < 4; ++fi)
            #pragma unroll
            for (int fj = 0; fj < 2; ++fj)
                #pragma unroll
                for (int ks = 0; ks < 2; ++ks)
                    acc[fi + 4][fj] = __builtin_amdgcn_mfma_f32_16x16x32_bf16(a[fi][ks], b0[fj][ks], acc[fi + 4][fj], 0, 0, 0);
        __builtin_amdgcn_s_setprio(0);

        __builtin_amdgcn_sched_barrier(0);
        __builtin_amdgcn_s_barrier();
        __builtin_amdgcn_sched_barrier(0);
        if (t + 2 < 16) issueTile(t + 2, t & 1);
    }

    // ---- epilogue: C col = lr (n), row = lg*4 + i (m) ----
    const int w = n0 >> 10;            // tile spans one weight (256 | 1024)
    const float qs = (w == 0) ? 0.125f * 1.44269504f : 1.0f;
    const int mb = m0 + wr * 128;
    const int nb = n0 + wc * 64;
    #pragma unroll
    for (int fi = 0; fi < 8; ++fi) {
        #pragma unroll
        for (int fj = 0; fj < 4; ++fj) {
            const int m = mb + fi * 16 + lg * 4;
            const int nn = (nb + fj * 16 + lr) & 1023;
            const int h = nn >> 6, d = nn & 63;
            const int bb = m >> 11, s = m & 2047;
            const size_t bh = (size_t)(bb * NH + h);
            if (w == 2) {
                u16x4 v;
                #pragma unroll
                for (int i = 0; i < 4; ++i) v[i] = f2bf(acc[fi][fj][i]);
                *(u16x4*)&VTo[(bh * HD + d) * SEQ + s] = v;
            } else {
                u16* P = (w == 0) ? Qo : Ko;
                #pragma unroll
                for (int i = 0; i < 4; ++i)
                    P[(bh * SEQ + s + i) * HD + d] = f2bf(acc[fi][fj][i] * qs);
            }
        }
    }
}

// ---------------------------------------------------------------------------
// GEMM (128x128 tile, BK=64, 2-phase) — used for the output projection only.
// ---------------------------------------------------------------------------
template<int MODE>
__global__ __launch_bounds__(256) void gemm_bt(
    const u16* __restrict__ A, const u16* __restrict__ Bb,
    u16* __restrict__ Qo, u16* __restrict__ Ko, u16* __restrict__ VTo,
    float* __restrict__ Fo)
{
    __shared__ u16 As[2][128 * 64];
    __shared__ u16 Bs[2][128 * 64];

    const int tid = threadIdx.x;
    const int m0 = blockIdx.x * 128;
    const int n0 = blockIdx.y * 128;

    const int lane = tid & 63;
    const int lr = lane & 15;
    const int lg = lane >> 4;
    const int wid = tid >> 6;
    const int wm = wid >> 1, wn = wid & 1;

    const int grow = lane >> 3;
    const int gcolb = ((lane & 7) ^ grow) << 4;
    const int rswz = (lr & 7);

    f32x4 acc[4][4] = {};

    auto issue = [&](int kt, int buf) {
        const int k0b = kt * 128;
        #pragma unroll
        for (int t = 0; t < 4; ++t) {
            const int row = (wid * 4 + t) * 8 + grow;
            gload16((const char*)A + (size_t)(m0 + row) * 2048 + k0b + gcolb,
                    (char*)As[buf] + (wid * 4 + t) * 1024);
            gload16((const char*)Bb + (size_t)(n0 + row) * 2048 + k0b + gcolb,
                    (char*)Bs[buf] + (wid * 4 + t) * 1024);
        }
    };

    issue(0, 0);

    for (int kt = 0; kt < 16; ++kt) {
        const int cur = kt & 1;
        __syncthreads();
        if (kt + 1 < 16) issue(kt + 1, cur ^ 1);

        const u16* Ac = As[cur];
        const u16* Bc = Bs[cur];
        #pragma unroll
        for (int kk = 0; kk < 2; ++kk) {
            short8 a[4], b[4];
            #pragma unroll
            for (int i = 0; i < 4; ++i)
                a[i] = *(const short8*)((const char*)Ac + (wm * 64 + i * 16 + lr) * 128
                                        + (((kk * 4 + lg) ^ rswz) << 4));
            #pragma unroll
            for (int i = 0; i < 4; ++i)
                b[i] = *(const short8*)((const char*)Bc + (wn * 64 + i * 16 + lr) * 128
                                        + (((kk * 4 + lg) ^ rswz) << 4));
            #pragma unroll
            for (int mi = 0; mi < 4; ++mi)
                #pragma unroll
                for (int ni = 0; ni < 4; ++ni)
                    acc[mi][ni] = __builtin_amdgcn_mfma_f32_16x16x32_bf16(a[mi], b[ni], acc[mi][ni], 0, 0, 0);
        }
    }

    const int mb = m0 + wm * 64;
    const int nb = n0 + wn * 64;
    #pragma unroll
    for (int mi = 0; mi < 4; ++mi)
        #pragma unroll
        for (int ni = 0; ni < 4; ++ni) {
            const int m = mb + mi * 16 + lg * 4;
            const int n = nb + ni * 16 + lr;
            #pragma unroll
            for (int i = 0; i < 4; ++i)
                Fo[(size_t)(m + i) * EMB + n] = acc[mi][ni][i];
        }
}

// ---------------------------------------------------------------------------
// Flash attention, swapped-operand, 8 waves x 16 q-rows = 128 q/block.
// (unchanged from R5 — known-pass)
// ---------------------------------------------------------------------------
__global__ __launch_bounds__(512) void attn_fwd(
    const u16* __restrict__ Q, const u16* __restrict__ K,
    const u16* __restrict__ VT, u16* __restrict__ Cat)
{
    __shared__ u16 Ks[2][64 * 64];     // [kv][e], 128B rows, XOR-swizzled
    __shared__ u16 Vs[2][80 * 64];     // [d][kv] rows 0..63; rows 64..79 = 1.0
    __shared__ u16 PT[8][16 * 72];     // per-wave P [q][kv], pad-72

    const int tid = threadIdx.x;
    const int lane = tid & 63;
    const int lr = lane & 15;
    const int lg = lane >> 4;
    const int wid = tid >> 6;
    const int qt = blockIdx.x;
    const int bh = blockIdx.y;
    const int b = bh >> 4, h = bh & 15;

    if (tid < 128) {
        const int row = 64 + (tid >> 3), sl = tid & 7;
        u16x8 ones;
        #pragma unroll
        for (int j = 0; j < 8; ++j) ones[j] = 0x3F80;
        *(u16x8*)((char*)Vs[0] + row * 128 + ((sl ^ (row & 7)) << 4)) = ones;
        *(u16x8*)((char*)Vs[1] + row * 128 + ((sl ^ (row & 7)) << 4)) = ones;
    }

    const u16* Qg = Q + ((size_t)bh * SEQ + qt * 128 + wid * 16 + lr) * HD;
    short8 qf[2];
    qf[0] = *(const short8*)(Qg + lg * 8);
    qf[1] = *(const short8*)(Qg + 32 + lg * 8);

    float m = -1e30f;
    f32x4 accO[5] = {};

    const u16* Kg = K + (size_t)bh * SEQ * HD;
    const u16* Vg = VT + (size_t)bh * HD * SEQ;

    const int srow = lane >> 3;
    const int schunk = ((lane & 7) ^ srow) << 4;

    auto issueKV = [&](int nt, int buf) {
        const int kv0 = nt * 64;
        const int krow = wid * 8 + srow;
        gload16((const char*)Kg + (size_t)(kv0 + krow) * 128 + schunk,
                (char*)Ks[buf] + wid * 1024);
        gload16((const char*)Vg + (size_t)krow * (SEQ * 2) + kv0 * 2 + schunk,
                (char*)Vs[buf] + wid * 1024);
    };

    issueKV(0, 0);

    for (int nt = 0; nt < SEQ / 64; ++nt) {
        const int cur = nt & 1;
        __syncthreads();
        if (nt + 1 < SEQ / 64) issueKV(nt + 1, cur ^ 1);

        f32x4 st[4] = {};
        #pragma unroll
        for (int kk = 0; kk < 2; ++kk) {
            const short8 qv = qf[kk];
            #pragma unroll
            for (int c = 0; c < 4; ++c) {
                const short8 kf = *(const short8*)((const char*)Ks[cur] + (c * 16 + lr) * 128
                                                   + (((kk * 4 + lg) ^ (lr & 7)) << 4));
                st[c] = __builtin_amdgcn_mfma_f32_16x16x32_bf16(kf, qv, st[c], 0, 0, 0);
            }
        }

        float mx = fmaxf(
            fmaxf(fmaxf(fmaxf(st[0][0], st[0][1]), fmaxf(st[0][2], st[0][3])),
                  fmaxf(fmaxf(st[1][0], st[1][1]), fmaxf(st[1][2], st[1][3]))),
            fmaxf(fmaxf(fmaxf(st[2][0], st[2][1]), fmaxf(st[2][2], st[2][3])),
                  fmaxf(fmaxf(st[3][0], st[3][1]), fmaxf(st[3][2], st[3][3]))));
        mx = fmaxf(mx, __shfl_xor(mx, 16));
        mx = fmaxf(mx, __shfl_xor(mx, 32));
        if (!__all(mx - m <= 11.5f)) {
            const float nm = fmaxf(m, mx);
            const float corr = fexp2(m - nm);
            m = nm;
            #pragma unroll
            for (int dc = 0; dc < 5; ++dc)
                accO[dc] *= corr;
        }
        #pragma unroll
        for (int c = 0; c < 4; ++c)
            #pragma unroll
            for (int i = 0; i < 4; ++i)
                st[c][i] = fexp2(st[c][i] - m);

        #pragma unroll
        for (int c = 0; c < 4; ++c) {
            u32 w0, w1;
            asm("v_cvt_pk_bf16_f32 %0, %1, %2" : "=v"(w0) : "v"(st[c][0]), "v"(st[c][1]));
            asm("v_cvt_pk_bf16_f32 %0, %1, %2" : "=v"(w1) : "v"(st[c][2]), "v"(st[c][3]));
            u32x2 pk; pk[0] = w0; pk[1] = w1;
            *(u32x2*)&PT[wid][lr * 72 + c * 16 + lg * 4] = pk;
        }
        asm volatile("s_waitcnt lgkmcnt(0)" ::: "memory");
        __builtin_amdgcn_sched_barrier(0);

        #pragma unroll
        for (int kk = 0; kk < 2; ++kk) {
            const short8 pf = *(const short8*)&PT[wid][lr * 72 + kk * 32 + lg * 8];
            #pragma unroll
            for (int dc = 0; dc < 5; ++dc) {
                const short8 vf = *(const short8*)((const char*)Vs[cur] + (dc * 16 + lr) * 128
                                                   + (((kk * 4 + lg) ^ (lr & 7)) << 4));
                accO[dc] = __builtin_amdgcn_mfma_f32_16x16x32_bf16(vf, pf, accO[dc], 0, 0, 0);
            }
        }
    }

    const float invl = 1.f / accO[4][0];
    const int qs = qt * 128 + wid * 16 + lr;
    u16* ob = Cat + (size_t)b * SEQ * EMB + (size_t)qs * EMB + h * HD;
    #pragma unroll
    for (int dc = 0; dc < 4; ++dc) {
        u16x4 o;
        #pragma unroll
        for (int i = 0; i < 4; ++i) o[i] = f2bf(accO[dc][i] * invl);
        *(u16x4*)&ob[dc * 16 + lg * 4] = o;
    }
}

// ---------------------------------------------------------------------------
extern "C" void kernel_launch(void* const* d_in, const int* in_sizes, int n_in,
                              void* d_out, int out_size, void* d_ws, size_t ws_size,
                              hipStream_t stream) {
    const float* x  = (const float*)d_in[0];
    const float* Wq = (const float*)d_in[1];
    const float* Wk = (const float*)d_in[2];
    const float* Wv = (const float*)d_in[3];
    const float* Wo = (const float*)d_in[4];
    float* out = (float*)d_out;

    // d_out (16MB) doubles as bf16 staging for Xb+Wqkv (dead before gemm<1>
    // overwrites d_out with the final f32 result).
    u16* Xb   = (u16*)d_out;                          // [4096][1024] bf16
    u16* Wqkv = (u16*)d_out + (size_t)4 * 1048576;    // [3072][1024] bf16

    char* ws = (char*)d_ws;
    u16* Qb  = (u16*)(ws);                            // [B,H,S,64]  8MB
    u16* Kb  = (u16*)(ws + (size_t)8  * 1048576);     // [B,H,S,64]  8MB
    u16* VTb = (u16*)(ws + (size_t)16 * 1048576);     // [B,H,64,S]  8MB
    u16* Cat = (u16*)(ws + (size_t)24 * 1048576);     // [B,S,E]     8MB
    u16* Wob = Qb;                                    // Qb dead after attn

    convert_all<<<3584, 256, 0, stream>>>(x, Wq, Wk, Wv, Xb, Wqkv);

    // QKV projection: M=4096, N=3072, K=1024 (Q pre-scaled by 0.125*log2e)
    dim3 g1(4096 / 256, 3072 / 256);
    gemm256<<<g1, 512, 0, stream>>>(Xb, Wqkv, Qb, Kb, VTb);

    // Attention (128 q-rows/block, 8 waves)
    dim3 g2(SEQ / 128, BATCH * NH);
    attn_fwd<<<g2, 512, 0, stream>>>(Qb, Kb, VTb, Cat);

    // Wo -> bf16 into Qb region, then output projection M=4096,N=1024,K=1024
    convert_wo<<<512, 256, 0, stream>>>(Wo, Wob);
    dim3 g3(4096 / 128, 1024 / 128);
    gemm_bt<1><<<g3, 256, 0, stream>>>(Cat, Wob, nullptr, nullptr, nullptr, out);
}